// Round 7
// baseline (203.244 us; speedup 1.0000x reference)
//
#include <hip/hip_runtime.h>

// Problem constants: A=1, B=8, M=256, H=2048, E=8, K=2, N=2048
#define Bn 8
#define Mn 256
#define Hn 2048
#define En 8
#define Kn 2
#define Nn 2048

typedef float vf4 __attribute__((ext_vector_type(4)));

// d_ws layout (floats):
//   hs     [Bn*Hn]        64 KB  -- hidden column sums        (write-once)
//   wsum   [En*Hn]        64 KB  -- gup row sums              (write-once, by wreduce)
//   partial[En*Hn * 64]    4 MB  -- per-lane gup row partials (write-once)

// blocks [0, 128):    hidden full-column sums -> hs[b*Hn + k]  (proven R5/R6 design).
// blocks [128, 1152): gup row partials. 4096 waves, wave w owns rows [4w, 4w+4).
//                     Prefetch distance 2 (issue row j+2 right after consuming j):
//                     8-16 KB in flight per wave, NO cross-lane ops in the loop —
//                     per row: 8 nt loads, 10 adds, one coalesced 256 B/wave store.
__global__ void reduce_kernel(const float* __restrict__ hidden,
                              const float* __restrict__ gup,
                              float* __restrict__ hs,
                              float* __restrict__ partial) {
    const int bid = blockIdx.x;
    const int t   = threadIdx.x;
    if (bid < 128) {
        const int b   = bid >> 4;
        const int kh  = bid & 15;
        const int col = t & 31;          // float4 column within 128-float slice
        const int mg  = t >> 5;          // m-group: 32 rows each
        const vf4* hp = (const vf4*)(hidden + ((size_t)b * Mn + mg * 32) * Hn)
                        + kh * 32 + col;
        vf4 a0 = 0.f, a1 = 0.f, a2 = 0.f, a3 = 0.f;
#pragma unroll
        for (int m = 0; m < 32; m += 4) {
            vf4 v0 = __builtin_nontemporal_load(hp + (size_t)(m + 0) * (Hn / 4));
            vf4 v1 = __builtin_nontemporal_load(hp + (size_t)(m + 1) * (Hn / 4));
            vf4 v2 = __builtin_nontemporal_load(hp + (size_t)(m + 2) * (Hn / 4));
            vf4 v3 = __builtin_nontemporal_load(hp + (size_t)(m + 3) * (Hn / 4));
            a0 += v0; a1 += v1; a2 += v2; a3 += v3;
        }
        vf4 s = (a0 + a1) + (a2 + a3);
        __shared__ vf4 sd[8][32];
        sd[mg][col] = s;
        __syncthreads();
        if (t < 32) {
            vf4 r = sd[0][t];
#pragma unroll
            for (int g = 1; g < 8; ++g) r += sd[g][t];
            ((vf4*)hs)[(size_t)b * (Hn / 4) + kh * 32 + t] = r;
        }
    } else {
        const int wave = (bid - 128) * 4 + (t >> 6);   // 0..4095
        const int lane = t & 63;
        const size_t r0 = (size_t)wave * 4;            // first of 4 rows
        const vf4* base = (const vf4*)gup + r0 * (Nn / 4) + lane;
        vf4 buf[2][8];
#pragma unroll
        for (int i = 0; i < 8; ++i)
            buf[0][i] = __builtin_nontemporal_load(base + 0 * (Nn / 4) + i * 64);
#pragma unroll
        for (int i = 0; i < 8; ++i)
            buf[1][i] = __builtin_nontemporal_load(base + 1 * (Nn / 4) + i * 64);
        float* pout = partial + r0 * 64 + lane;
#pragma unroll
        for (int j = 0; j < 4; ++j) {
            vf4* cur = buf[j & 1];
            vf4 v = ((cur[0] + cur[1]) + (cur[2] + cur[3]))
                  + ((cur[4] + cur[5]) + (cur[6] + cur[7]));
            float s = (v.x + v.y) + (v.z + v.w);
            __builtin_nontemporal_store(s, pout + j * 64);  // partial[(r0+j)*64+lane]
            if (j < 2) {
#pragma unroll
                for (int i = 0; i < 8; ++i)                 // refill with row j+2
                    cur[i] = __builtin_nontemporal_load(
                        base + (size_t)(j + 2) * (Nn / 4) + i * 64);
            }
        }
    }
}

// wsum[row] = sum_lane partial[row*64 + lane].  64 blocks x 4 waves; each wave
// owns 64 rows; one vf4 load covers 4 rows (lane group of 16 per row), then a
// 4-deep shuffle tree within each 16-lane group.
__global__ void wreduce_kernel(const float* __restrict__ partial,
                               float* __restrict__ wsum) {
    const int wave_g = blockIdx.x * 4 + (threadIdx.x >> 6);  // 0..255
    const int lane   = threadIdx.x & 63;
    const int r0     = wave_g * 64;
    const vf4* p = (const vf4*)partial;
#pragma unroll 4
    for (int j = 0; j < 64; j += 4) {
        // 256 floats = rows r0+j .. r0+j+3; lanes 0-15 -> row j, 16-31 -> j+1, ...
        vf4 v = p[(size_t)(r0 + j) * 16 + lane];
        float s = (v.x + v.y) + (v.z + v.w);
        s += __shfl_down(s, 8, 64);
        s += __shfl_down(s, 4, 64);
        s += __shfl_down(s, 2, 64);
        s += __shfl_down(s, 1, 64);
        if ((lane & 15) == 0)
            wsum[r0 + j + (lane >> 4)] = s;
    }
}

// out = sum_{b,e,k} sp[b,e] * hs[b,k] * wsum[e,k]   (single block, 256 threads,
// reads only 128 KB)
__global__ void final_kernel(const float* __restrict__ sparsity,
                             const float* __restrict__ hs,
                             const float* __restrict__ wsum,
                             float* __restrict__ out) {
    __shared__ float sp[Bn][En];
    __shared__ float red[4];
    const int t = threadIdx.x;
    if (t < Bn * En) {
        const int b = t >> 3, e = t & 7;
        sp[b][e] = sparsity[b * (Kn * En) + e];   // sparsity[0, b, 0, e]
    }
    __syncthreads();
    float acc = 0.f;
#pragma unroll
    for (int i = 0; i < Hn / 256; ++i) {
        const int k = i * 256 + t;
        float h[Bn];
#pragma unroll
        for (int b = 0; b < Bn; ++b) h[b] = hs[b * Hn + k];
#pragma unroll
        for (int e = 0; e < En; ++e) {
            float g = 0.f;
#pragma unroll
            for (int b = 0; b < Bn; ++b) g += sp[b][e] * h[b];
            acc += wsum[e * Hn + k] * g;
        }
    }
#pragma unroll
    for (int off = 32; off > 0; off >>= 1)
        acc += __shfl_down(acc, off, 64);
    const int lane = t & 63, wave = t >> 6;
    if (lane == 0) red[wave] = acc;
    __syncthreads();
    if (t == 0) out[0] = (red[0] + red[1]) + (red[2] + red[3]);
}

extern "C" void kernel_launch(void* const* d_in, const int* in_sizes, int n_in,
                              void* d_out, int out_size, void* d_ws, size_t ws_size,
                              hipStream_t stream) {
    const float* hidden   = (const float*)d_in[0];  // (1,8,256,2048) fp32
    const float* sparsity = (const float*)d_in[1];  // (1,8,2,8) fp32
    const float* gup      = (const float*)d_in[2];  // (1,8,2048,2048) fp32

    float* hs      = (float*)d_ws;                  // 16384 floats
    float* wsum    = hs + Bn * Hn;                  // 16384 floats
    float* partial = wsum + En * Hn;                // 16384*64 floats (4 MB)

    reduce_kernel<<<128 + 1024, 256, 0, stream>>>(hidden, gup, hs, partial);
    wreduce_kernel<<<64, 256, 0, stream>>>(partial, wsum);
    final_kernel<<<1, 256, 0, stream>>>(sparsity, hs, wsum, (float*)d_out);
}